// Round 12
// baseline (25.751 us; speedup 1.0000x reference)
//
#include <hip/hip_runtime.h>
#include <math.h>

#define N        8192
#define BLK      256
#define RPT      4                    // a-points (rows) per thread
#define ROWS_BLK (BLK * RPT)          // 1024 rows per block
#define ITILES   (N / ROWS_BLK)       // 8
#define NSLICE   128                  // j-slices per direction
#define JCHUNK   (N / NSLICE)         // 64 b-points per slice
#define HALF     (ITILES * NSLICE)    // 1024 blocks per direction
#define GRID     (2 * HALF)           // 2048 = 8 blocks/CU, 32 waves/CU
#define RBLK     1024

typedef float v2f __attribute__((ext_vector_type(2)));

// ---------------------------------------------------- precompute + init ----
// P[0..N) = target {x,y,z,|p|^2}, P[N..2N) = output  (A-role, float4 AoS).
// Ppk: pair-transposed B-role layout, per point-pair group of 8 floats:
//   [x0 x1 y0 y1 z0 z1 w0 w1] -> v2f lanes line up for v_pk_fma_f32.
//   target groups at float offset 0, output groups at 4N.
// dmin[0..2N) = +inf bits.
__global__ __launch_bounds__(BLK) void chamfer_prep_kernel(
        const float* __restrict__ tgt, const float* __restrict__ outp,
        float4* __restrict__ P, float* __restrict__ Ppk,
        unsigned* __restrict__ dmin) {
    int i = blockIdx.x * BLK + (int)threadIdx.x;   // 0 .. 2N-1
    const float* src = (i < N) ? tgt : outp;
    int k = (i < N) ? i : (i - N);
    float x = src[3 * k + 0];
    float y = src[3 * k + 1];
    float z = src[3 * k + 2];
    float n2 = fmaf(x, x, fmaf(y, y, z * z));
    P[i] = make_float4(x, y, z, n2);

    int cbase = (i < N) ? 0 : 4 * N;       // cloud base (floats)
    int g = k >> 1, e = k & 1;
    float* q = Ppk + cbase + 8 * g + e;
    q[0] = x; q[2] = y; q[4] = z; q[6] = n2;

    dmin[i] = 0x7F800000u;  // +inf
}

// ---------------------------------------------------------------- dist ----
// Packed loop (v_pk_fma_f32 x3 per 2 points + v_min3, 2 inst/pair) with
// RPT=4: each thread owns FOUR a-rows, so each scalar B-fetch feeds 4 rows.
// Scalar-pipe traffic 8MB total; per-CU K$ working set 8 blocks x 1KB = 8KB
// (fits). GRID=2048 keeps full occupancy (32 waves/CU).
// d^2 = |a|^2 + (|b|^2 - 2 a.b); |a|^2 commutes with min.
__global__ __launch_bounds__(BLK) void chamfer_dist_kernel(
        const float4* __restrict__ P, const v2f* __restrict__ Ppk,
        unsigned* __restrict__ dmin) {
    int tid = (int)threadIdx.x;
    int bid = (int)blockIdx.x;
    int dir = (bid >= HALF) ? 1 : 0;
    if (dir) bid -= HALF;
    int aoff = dir ? N : 0;                 // A-role cloud (float4 index)
    int bpk  = dir ? 0 : 2 * N;             // B-role cloud base (v2f index)

    int itile = bid / NSLICE;
    int slice = bid % NSLICE;
    int i = itile * ROWS_BLK + tid;         // rows i + r*BLK, r<RPT

    v2f ax[RPT], ay[RPT], az[RPT];
    float aw[RPT];
    #pragma unroll
    for (int r = 0; r < RPT; ++r) {
        float4 a = P[aoff + i + r * BLK];   // coalesced
        float nx = -2.0f * a.x, ny = -2.0f * a.y, nz = -2.0f * a.z;
        ax[r] = (v2f){nx, nx};
        ay[r] = (v2f){ny, ny};
        az[r] = (v2f){nz, nz};
        aw[r] = a.w;
    }

    const float inf = __builtin_inff();
    float m0[RPT], m1[RPT];
    #pragma unroll
    for (int r = 0; r < RPT; ++r) { m0[r] = inf; m1[r] = inf; }

    // slice covers points [slice*JCHUNK, +JCHUNK) = JCHUNK/2 pair-groups,
    // 4 v2f per group -> v2f offset slice*(JCHUNK*2). Wave-uniform.
    const v2f* __restrict__ bp = Ppk + bpk + (size_t)slice * (JCHUNK * 2);

    #pragma unroll 2
    for (int g = 0; g < JCHUNK / 2; g += 2) {      // 2 pair-groups = 4 pts
        const v2f* q = bp + g * 4;
        v2f X0 = q[0], Y0 = q[1], Z0 = q[2], W0 = q[3];
        v2f X1 = q[4], Y1 = q[5], Z1 = q[6], W1 = q[7];
        #pragma unroll
        for (int r = 0; r < RPT; ++r) {
            v2f u0 = __builtin_elementwise_fma(ax[r], X0,
                     __builtin_elementwise_fma(ay[r], Y0,
                     __builtin_elementwise_fma(az[r], Z0, W0)));
            v2f u1 = __builtin_elementwise_fma(ax[r], X1,
                     __builtin_elementwise_fma(ay[r], Y1,
                     __builtin_elementwise_fma(az[r], Z1, W1)));
            m0[r] = fminf(fminf(m0[r], u0.x), u0.y);   // -> v_min3_f32
            m1[r] = fminf(fminf(m1[r], u1.x), u1.y);
        }
    }
    #pragma unroll
    for (int r = 0; r < RPT; ++r) {
        float d2 = fmaxf(aw[r] + fminf(m0[r], m1[r]), 0.0f);
        atomicMin(&dmin[aoff + i + r * BLK], __float_as_uint(d2));  // coalesced
    }
}

// -------------------------------------------------------------- reduce ----
__global__ __launch_bounds__(RBLK) void chamfer_reduce_kernel(
        const unsigned* __restrict__ dmin,
        const int* __restrict__ curp, const int* __restrict__ subp,
        float* __restrict__ out) {
    __shared__ float sh1[RBLK / 64], sh2[RBLK / 64];
    int t = (int)threadIdx.x;
    float s1 = 0.0f, s2 = 0.0f;
    const uint4* da = (const uint4*)dmin;          // dist1 as uint4
    const uint4* db = (const uint4*)(dmin + N);    // dist2 as uint4
    for (int i = t; i < N / 4; i += RBLK) {
        uint4 v1 = da[i], v2 = db[i];
        s1 += sqrtf(__uint_as_float(v1.x)) + sqrtf(__uint_as_float(v1.y))
            + sqrtf(__uint_as_float(v1.z)) + sqrtf(__uint_as_float(v1.w));
        s2 += sqrtf(__uint_as_float(v2.x)) + sqrtf(__uint_as_float(v2.y))
            + sqrtf(__uint_as_float(v2.z)) + sqrtf(__uint_as_float(v2.w));
    }
    #pragma unroll
    for (int off = 32; off > 0; off >>= 1) {
        s1 += __shfl_down(s1, off, 64);
        s2 += __shfl_down(s2, off, 64);
    }
    int wid = t >> 6, lane = t & 63;
    if (lane == 0) { sh1[wid] = s1; sh2[wid] = s2; }
    __syncthreads();
    if (t == 0) {
        float t1 = 0.0f, t2 = 0.0f;
        #pragma unroll
        for (int w = 0; w < RBLK / 64; ++w) { t1 += sh1[w]; t2 += sh2[w]; }
        int e = curp[0] / subp[0];
        double scale = 10.0 / pow(0.99, (double)e);
        out[0] = (float)((((double)t1 + (double)t2) / (double)N) * 0.5 * scale);
    }
}

// ---------------------------------------------------------------- launch ----
extern "C" void kernel_launch(void* const* d_in, const int* in_sizes, int n_in,
                              void* d_out, int out_size, void* d_ws, size_t ws_size,
                              hipStream_t stream) {
    const float* target = (const float*)d_in[0];   // (1, 8192, 3) f32
    const float* output = (const float*)d_in[1];   // (1, 8192, 3) f32
    const int*   curp   = (const int*)d_in[2];
    const int*   subp   = (const int*)d_in[3];
    float* out = (float*)d_out;

    // ws: float4 P[2N] (256KB) | float Ppk[8N] (256KB) | uint dmin[2N] (64KB)
    float4*   P    = (float4*)d_ws;
    float*    Ppk  = (float*)(P + 2 * N);
    unsigned* dmin = (unsigned*)(Ppk + 8 * N);

    chamfer_prep_kernel<<<2 * N / BLK, BLK, 0, stream>>>(target, output, P, Ppk, dmin);
    chamfer_dist_kernel<<<GRID, BLK, 0, stream>>>(P, (const v2f*)Ppk, dmin);
    chamfer_reduce_kernel<<<1, RBLK, 0, stream>>>(dmin, curp, subp, out);
}